// Round 11
// baseline (415.197 us; speedup 1.0000x reference)
//
#include <hip/hip_runtime.h>

// ResidualVQ: B=8, T=2048, D=256, Q=8, K=1024. N = B*T = 16384.
// Scoring via fp16 split-MFMA: 2x = xh + xl, e = eh + el (fp16 RTNE).
// 2x.e ~= xh.eh + xh.el + xl.eh  (dropped xl.el ~ 2e-6, below fp32 noise).
// One GEMM, reduce length 768, mapped into 512-wide packed buffers:
//   d' in [0,512):   A: ecat col d' (eh|el)    B: xcat col (d' < 256 ? d' : d'-256)
//   d' in [512,768): A: ecat col d'-512 (eh)   B: xcat col d'-256 (xl)
// score = acc - |e|^2  (row-constant |x|^2 dropped; same argmax).
//
// ROUND 11 = round 10 + occupancy: grid 512 (2 blocks/CU, 4 waves/SIMD),
// 128-token tiles, 3-buffer LDS ring (77 KB/block), wave tile 64x64
// (acc[4][4] = 64 VGPR, fits the 128-VGPR cap of launch_bounds(512,4)).
// Rationale: round-10 GEMM was barrier-lockstep-bound at 1 block/CU; a
// second co-resident block fills each other's ds_read/barrier stalls.
// xcat stays parity double-buffered (round-10 race fix).
//
// d_out (float): [0, N*D) quantized_out; [N*D,+Q*N) indices; [+Q) losses
// d_ws: xb f16[2][N][512] | ecat f16[Q*K][512] | norms f32[Q*K]
//       | partial float2[2][4][N] (layer-parity double buffer)

typedef _Float16 f16;
typedef f16 f16x8 __attribute__((ext_vector_type(8)));
typedef float f32x4 __attribute__((ext_vector_type(4)));

constexpr int Dd = 256;
constexpr int Kk = 1024;
constexpr int Qq = 8;
constexpr int Nn = 16384;

__device__ inline void gload16(const f16* g, f16* l) {
    __builtin_amdgcn_global_load_lds(
        (const __attribute__((address_space(1))) unsigned int*)(const __attribute__((address_space(1))) f16*)g,
        (__attribute__((address_space(3))) unsigned int*)(__attribute__((address_space(3))) f16*)l,
        16, 0, 0);
}

// ---- build ecat[Q*K][512] = [eh|el] + squared norms, from fp32 codebooks ----
__global__ __launch_bounds__(256) void build_ecat(const float* __restrict__ cb,
                                                  f16* __restrict__ ecat,
                                                  float* __restrict__ norms) {
    int row = blockIdx.x * 8 + (threadIdx.x >> 5);
    int p = threadIdx.x & 31;
    const float* s = cb + (size_t)row * Dd + p * 8;
    f16x8 hi, lo;
    float sq = 0.f;
#pragma unroll
    for (int j = 0; j < 8; ++j) {
        float v = s[j];
        f16 h = (f16)v;
        hi[j] = h; lo[j] = (f16)(v - (float)h);
        sq = fmaf(v, v, sq);
    }
    *(f16x8*)(ecat + (size_t)row * 512 + p * 8) = hi;
    *(f16x8*)(ecat + (size_t)row * 512 + 256 + p * 8) = lo;
#pragma unroll
    for (int off = 16; off >= 1; off >>= 1) sq += __shfl_down(sq, off, 32);
    if (p == 0) norms[row] = sq;
}

// ---- score layer q (+fused update of layer q-1) ----
// block = 256-code slice x 128 tokens, 8 waves (4 code-quarter x 2 token-half)
__global__ __launch_bounds__(512, 4) void score_kernel(
    const float* __restrict__ x,        // [N][256]
    const float* __restrict__ cb_prev,  // layer q-1 codebook [K][256] (q>0)
    const f16* __restrict__ ecat,       // this layer [K][512]
    const float* __restrict__ norms,    // this layer [K]
    const f16* __restrict__ xold,       // xb[(q-1)&1] (q>0 src; stable)
    f16* __restrict__ xnew,             // xb[q&1] (written; GEMM input)
    const float2* __restrict__ pin,     // partial layer q-1
    float2* __restrict__ pout,          // partial layer q
    float* __restrict__ idx_prev,       // [N] (q>0, slice0)
    float* __restrict__ loss_prev,      // scalar (q>0, slice0)
    int q)
{
    __shared__ f16 sA[3][8192];       // 3 x 16 KB: 256 codes x 32 cols
    __shared__ f16 sB[3][4096];       // 3 x  8 KB: 128 tokens x 32 cols
    __shared__ float smn[256];
    __shared__ float2 smg[4][128];
    __shared__ float lred[8];

    const int tid = threadIdx.x;
    const int w = tid >> 6, l = tid & 63;
    const int wrq = w >> 1, wch = w & 1;        // wrq: code quarter, wch: token half
    const int l16 = l & 15, hi4 = l >> 4;

    // XCD-aligned: 4 slice-blocks of one 128-token tile share (b & 7).
    const int b = blockIdx.x;
    const int slice = (b >> 3) & 3;             // 256-code slice
    const int tokt = ((b >> 5) << 3) | (b & 7); // 128 token tiles
    const int tbase = tokt * 128;
    const int qcb = slice * 256;

    // ================= fused update phase (layer q-1 -> xnew tile) ====
    {
        const int up = tid & 15;
        const int d0 = up * 16;
        float lp = 0.f;
#pragma unroll 1
        for (int pass = 0; pass < 4; ++pass) {
            const int row = tbase + pass * 32 + (tid >> 4);
            f16* xw = xnew + (size_t)row * 512;
            if (q == 0) {
                const float* xs = x + (size_t)row * Dd + d0;
#pragma unroll
                for (int c = 0; c < 2; ++c) {
                    f16x8 hi, lo;
#pragma unroll
                    for (int j = 0; j < 8; ++j) {
                        float v = 2.f * xs[c * 8 + j];
                        f16 h = (f16)v;
                        hi[j] = h; lo[j] = (f16)(v - (float)h);
                    }
                    *(f16x8*)(xw + d0 + c * 8) = hi;
                    *(f16x8*)(xw + 256 + d0 + c * 8) = lo;
                }
            } else {
                float2 bsel = pin[row];
#pragma unroll
                for (int s2 = 1; s2 < 4; ++s2) {
                    float2 c2 = pin[(size_t)s2 * Nn + row];
                    if (c2.x > bsel.x || (c2.x == bsel.x && c2.y < bsel.y)) bsel = c2;
                }
                const int k = (int)bsel.y;
                const float4* e4 = (const float4*)(cb_prev + (size_t)k * Dd + d0);
                float e[16];
#pragma unroll
                for (int c = 0; c < 4; ++c) {
                    float4 v = e4[c];
                    e[c * 4 + 0] = v.x; e[c * 4 + 1] = v.y;
                    e[c * 4 + 2] = v.z; e[c * 4 + 3] = v.w;
                }
                const f16* xr = xold + (size_t)row * 512;
                f16x8 h0 = *(const f16x8*)(xr + d0);
                f16x8 h1 = *(const f16x8*)(xr + d0 + 8);
                f16x8 l0 = *(const f16x8*)(xr + 256 + d0);
                f16x8 l1 = *(const f16x8*)(xr + 256 + d0 + 8);
                float rn[16];
#pragma unroll
                for (int j = 0; j < 8; ++j) {
                    rn[j]     = ((float)h0[j] + (float)l0[j]) * 0.5f - e[j];
                    rn[8 + j] = ((float)h1[j] + (float)l1[j]) * 0.5f - e[8 + j];
                }
#pragma unroll
                for (int j = 0; j < 16; ++j) lp = fmaf(rn[j], rn[j], lp);
                f16* xw2 = xnew + (size_t)row * 512;
#pragma unroll
                for (int c = 0; c < 2; ++c) {
                    f16x8 hi, lo;
#pragma unroll
                    for (int j = 0; j < 8; ++j) {
                        float v = 2.f * rn[c * 8 + j];
                        f16 h = (f16)v;
                        hi[j] = h; lo[j] = (f16)(v - (float)h);
                    }
                    *(f16x8*)(xw2 + d0 + c * 8) = hi;
                    *(f16x8*)(xw2 + 256 + d0 + c * 8) = lo;
                }
                if (slice == 0 && up == 0) idx_prev[row] = (float)k;
                (void)xw;
            }
        }
        if (q > 0 && slice == 0) {
#pragma unroll
            for (int off = 32; off >= 1; off >>= 1) lp += __shfl_down(lp, off);
            if (l == 0) lred[w] = lp;
        }
    }
    if (tid < 256) smn[tid] = norms[qcb + tid];
    __syncthreads();   // drains vmcnt(0): xnew stores visible to gload_lds
    if (q > 0 && slice == 0 && tid == 0) {
        float s = 0.f;
#pragma unroll
        for (int i = 0; i < 8; ++i) s += lred[i];
        atomicAdd(loss_prev, s * (1.0f / ((float)Nn * (float)Dd)));
    }

    // ================= GEMM phase =================
    // Staging: A-tile 1024 chunks (2/thread), B-tile 512 chunks (1/thread);
    // source col-chunk pre-swizzled: g = (t&3) ^ ((t>>3)&3)  [= (row>>1)&3].
    const int srow = tid >> 2;
    const int g = ((tid & 3) ^ ((tid >> 3) & 3)) * 8;
    const f16* ga0 = ecat + (size_t)(qcb + srow) * 512 + g;
    const f16* ga1 = ga0 + (size_t)128 * 512;
    const f16* gb0 = xnew + (size_t)(tbase + srow) * 512 + g;

    // ds_read offsets with the same involution: cc = hi4 ^ ((row>>1)&3)
    int offA[4], offB[4];
#pragma unroll
    for (int m = 0; m < 4; ++m) {
        int row = wrq * 64 + m * 16 + l16;
        offA[m] = row * 32 + ((hi4 ^ ((row >> 1) & 3)) * 8);
    }
#pragma unroll
    for (int n = 0; n < 4; ++n) {
        int row = wch * 64 + n * 16 + l16;
        offB[n] = row * 32 + ((hi4 ^ ((row >> 1) & 3)) * 8);
    }

    f32x4 acc[4][4];
#pragma unroll
    for (int m = 0; m < 4; ++m)
#pragma unroll
        for (int n = 0; n < 4; ++n) acc[m][n] = (f32x4){0.f, 0.f, 0.f, 0.f};

#define STAGE(NB, J) do { \
        int d0s = (J) * 32; \
        int aoff = d0s < 512 ? d0s : d0s - 512; \
        int boff = d0s < 256 ? d0s : d0s - 256; \
        gload16(ga0 + aoff, &sA[NB][tid * 8]); \
        gload16(ga1 + aoff, &sA[NB][4096 + tid * 8]); \
        gload16(gb0 + boff, &sB[NB][tid * 8]); \
    } while (0)

    // prologue: K-tiles 0,1 in flight (3 loads each); wait tile 0 -> vmcnt(3)
    STAGE(0, 0);
    STAGE(1, 1);
    asm volatile("s_waitcnt vmcnt(3)\n\ts_barrier" ::: "memory");

#pragma unroll
    for (int j = 0; j < 24; ++j) {
        const int buf = j % 3;
        if (j + 2 < 24) STAGE((j + 2) % 3, j + 2);
        f16x8 bf[4], af[4];
#pragma unroll
        for (int n = 0; n < 4; ++n) bf[n] = *(const f16x8*)&sB[buf][offB[n]];
#pragma unroll
        for (int m = 0; m < 4; ++m) af[m] = *(const f16x8*)&sA[buf][offA[m]];
        __builtin_amdgcn_s_setprio(1);
#pragma unroll
        for (int m = 0; m < 4; ++m)
#pragma unroll
            for (int n = 0; n < 4; ++n)
                acc[m][n] = __builtin_amdgcn_mfma_f32_16x16x32_f16(af[m], bf[n], acc[m][n], 0, 0, 0);
        __builtin_amdgcn_s_setprio(0);
        if (j < 23) {
            if (j < 22) asm volatile("s_waitcnt vmcnt(3)\n\ts_barrier" ::: "memory");
            else        asm volatile("s_waitcnt vmcnt(0)\n\ts_barrier" ::: "memory");
        }
    }
#undef STAGE

    // epilogue: score = acc - |e|^2 ; top-1 (ascending code order)
    float bv[4]; int bi[4];
#pragma unroll
    for (int n = 0; n < 4; ++n) { bv[n] = -3.4e38f; bi[n] = 0; }
#pragma unroll
    for (int m = 0; m < 4; ++m) {
#pragma unroll
        for (int r = 0; r < 4; ++r) {
            int cl = wrq * 64 + m * 16 + hi4 * 4 + r;   // code local in 256-slice
            float nrm = smn[cl];
            int cg = qcb + cl;
#pragma unroll
            for (int n = 0; n < 4; ++n) {
                float v = acc[m][n][r] - nrm;
                if (v > bv[n]) { bv[n] = v; bi[n] = cg; }
            }
        }
    }
    // merge across the lane>>4 groups (same token, different codes)
#pragma unroll
    for (int off = 16; off <= 32; off <<= 1) {
#pragma unroll
        for (int n = 0; n < 4; ++n) {
            float ov = __shfl_xor(bv[n], off);
            int oi = __shfl_xor(bi[n], off);
            if (ov > bv[n] || (ov == bv[n] && oi < bi[n])) { bv[n] = ov; bi[n] = oi; }
        }
    }
    if (l < 16) {
#pragma unroll
        for (int n = 0; n < 4; ++n)
            smg[wrq][wch * 64 + n * 16 + l] = make_float2(bv[n], (float)bi[n]);
    }
    __syncthreads();
    // merge the 4 code-quarter wave groups
    if (tid < 128) {
        float2 r = smg[0][tid];
#pragma unroll
        for (int ww = 1; ww < 4; ++ww) {
            float2 c = smg[ww][tid];
            if (c.x > r.x || (c.x == r.x && c.y < r.y)) r = c;
        }
        pout[(size_t)slice * Nn + tbase + tid] = r;
    }
}

// ---- final: merge partial(7), idx7, loss7, out = x - r8 ----
__global__ __launch_bounds__(256) void final_kernel(
    const float* __restrict__ x,
    const float* __restrict__ cb7,      // layer 7 codebook
    const f16* __restrict__ xcat,       // xb[1]: holds split(2*r7)
    const float2* __restrict__ pin,     // partial layer 7
    float* __restrict__ out,
    float* __restrict__ idx7,
    float* __restrict__ loss7)
{
    __shared__ float lsum[4];
    const int tid = threadIdx.x;
    const int row = blockIdx.x * 16 + (tid >> 4);
    const int d0 = (tid & 15) * 16;

    float2 bsel = pin[row];
#pragma unroll
    for (int s2 = 1; s2 < 4; ++s2) {
        float2 c2 = pin[(size_t)s2 * Nn + row];
        if (c2.x > bsel.x || (c2.x == bsel.x && c2.y < bsel.y)) bsel = c2;
    }
    const int k = (int)bsel.y;
    const float* e = cb7 + (size_t)k * Dd + d0;
    const f16* xr = xcat + (size_t)row * 512;
    const float* xs = x + (size_t)row * Dd + d0;
    float* os = out + (size_t)row * Dd + d0;

    f16x8 h0 = *(const f16x8*)(xr + d0);
    f16x8 h1 = *(const f16x8*)(xr + d0 + 8);
    f16x8 l0 = *(const f16x8*)(xr + 256 + d0);
    f16x8 l1 = *(const f16x8*)(xr + 256 + d0 + 8);
    float lp = 0.f;
#pragma unroll
    for (int j = 0; j < 8; ++j) {
        float r7a = ((float)h0[j] + (float)l0[j]) * 0.5f;
        float r7b = ((float)h1[j] + (float)l1[j]) * 0.5f;
        float r8a = r7a - e[j];
        float r8b = r7b - e[8 + j];
        os[j]     = xs[j] - r8a;
        os[8 + j] = xs[8 + j] - r8b;
        lp = fmaf(r8a, r8a, lp);
        lp = fmaf(r8b, r8b, lp);
    }
    if ((tid & 15) == 0) idx7[row] = (float)k;

#pragma unroll
    for (int off = 32; off >= 1; off >>= 1) lp += __shfl_down(lp, off);
    if ((tid & 63) == 0) lsum[tid >> 6] = lp;
    __syncthreads();
    if (tid == 0) {
        float s = lsum[0] + lsum[1] + lsum[2] + lsum[3];
        atomicAdd(loss7, s * (1.0f / ((float)Nn * (float)Dd)));
    }
}

extern "C" void kernel_launch(void* const* d_in, const int* in_sizes, int n_in,
                              void* d_out, int out_size, void* d_ws, size_t ws_size,
                              hipStream_t stream) {
    const float* x   = (const float*)d_in[0];   // [N,D]
    const float* cbs = (const float*)d_in[1];   // [Q,K,D]
    float* out    = (float*)d_out;
    float* idxs   = out + (size_t)Nn * Dd;        // [Q*N]
    float* losses = idxs + (size_t)Qq * Nn;       // [Q]

    f16* xb0     = (f16*)d_ws;                          // [N][512]
    f16* xb1     = xb0 + (size_t)Nn * 512;              // [N][512]
    f16* ecat    = xb1 + (size_t)Nn * 512;              // [Q*K][512]
    float* norms = (float*)(ecat + (size_t)Qq * Kk * 512);  // [Q*K]
    float2* part0 = (float2*)(norms + (size_t)Qq * Kk);     // [4][N]
    float2* part1 = part0 + (size_t)4 * Nn;                 // [4][N]

    hipMemsetAsync(losses, 0, Qq * sizeof(float), stream);
    build_ecat<<<(Qq * Kk) / 8, 256, 0, stream>>>(cbs, ecat, norms);

    for (int q = 0; q < Qq; ++q) {
        float2* pin  = (q & 1) ? part1 : part0;   // layer q-1 partials
        float2* pout = (q & 1) ? part0 : part1;   // layer q partials
        const f16* xold = (q & 1) ? xb0 : xb1;    // xb[(q-1)&1]
        f16* xnew       = (q & 1) ? xb1 : xb0;    // xb[q&1]
        score_kernel<<<512, 512, 0, stream>>>(
            x,
            q > 0 ? cbs + (size_t)(q - 1) * Kk * Dd : cbs,
            ecat + (size_t)q * Kk * 512, norms + (size_t)q * Kk,
            xold, xnew, pin, pout,
            q > 0 ? idxs + (size_t)(q - 1) * Nn : idxs,
            q > 0 ? losses + (q - 1) : losses,
            q);
    }
    // layer 7 partials: q=7 odd -> pout = part0; r7 split lives in xb[1]
    final_kernel<<<Nn / 16, 256, 0, stream>>>(
        x, cbs + (size_t)7 * Kk * Dd, xb1, part0, out,
        idxs + (size_t)7 * Nn, losses + 7);
}

// Round 12
// 334.081 us; speedup vs baseline: 1.2428x; 1.2428x over previous
//
#include <hip/hip_runtime.h>

// ResidualVQ: B=8, T=2048, D=256, Q=8, K=1024. N = B*T = 16384.
// Scoring via fp16 split-MFMA: 2x = xh + xl, e = eh + el (fp16 RTNE).
// 2x.e ~= xh.eh + xh.el + xl.eh  (dropped xl.el ~ 2e-6, below fp32 noise).
// score = acc - |e|^2  (row-constant |x|^2 dropped; same argmax).
//
// ROUND 12 = round 10 + operand-sharing chunk reorder in the GEMM:
// the 24 K-tiles = 8 col-chunks x 3 products {eh*xh, el*xh, eh*xl}.
// Per chunk stage the 4 DISTINCT operands once (8 gloads, was 12),
// read 24 frags (was 36: aeh shared by seg1+seg3, bxh by seg1+seg2),
// 96 MFMAs between barriers (was 32), ONE vmcnt(0)+barrier per chunk
// (was 3). Parity-2 LDS ring: 8 units x 16 KB = 128 KB, 1 block/CU.
// Update phase, epilogue, final kernel: identical to round 10.
//
// d_out (float): [0, N*D) quantized_out; [N*D,+Q*N) indices; [+Q) losses
// d_ws: xb f16[2][N][512] | ecat f16[Q*K][512] | norms f32[Q*K]
//       | partial float2[2][4][N] (layer-parity double buffer)

typedef _Float16 f16;
typedef f16 f16x8 __attribute__((ext_vector_type(8)));
typedef float f32x4 __attribute__((ext_vector_type(4)));

constexpr int Dd = 256;
constexpr int Kk = 1024;
constexpr int Qq = 8;
constexpr int Nn = 16384;

__device__ inline void gload16(const f16* g, f16* l) {
    __builtin_amdgcn_global_load_lds(
        (const __attribute__((address_space(1))) unsigned int*)(const __attribute__((address_space(1))) f16*)g,
        (__attribute__((address_space(3))) unsigned int*)(__attribute__((address_space(3))) f16*)l,
        16, 0, 0);
}

// ---- build ecat[Q*K][512] = [eh|el] + squared norms, from fp32 codebooks ----
__global__ __launch_bounds__(256) void build_ecat(const float* __restrict__ cb,
                                                  f16* __restrict__ ecat,
                                                  float* __restrict__ norms) {
    int row = blockIdx.x * 8 + (threadIdx.x >> 5);
    int p = threadIdx.x & 31;
    const float* s = cb + (size_t)row * Dd + p * 8;
    f16x8 hi, lo;
    float sq = 0.f;
#pragma unroll
    for (int j = 0; j < 8; ++j) {
        float v = s[j];
        f16 h = (f16)v;
        hi[j] = h; lo[j] = (f16)(v - (float)h);
        sq = fmaf(v, v, sq);
    }
    *(f16x8*)(ecat + (size_t)row * 512 + p * 8) = hi;
    *(f16x8*)(ecat + (size_t)row * 512 + 256 + p * 8) = lo;
#pragma unroll
    for (int off = 16; off >= 1; off >>= 1) sq += __shfl_down(sq, off, 32);
    if (p == 0) norms[row] = sq;
}

// ---- score layer q (+fused update of layer q-1) ----
// block = 256-code slice x 256 tokens, 8 waves (2 code-half x 4 token-quarter)
__global__ __launch_bounds__(512, 2) void score_kernel(
    const float* __restrict__ x,        // [N][256]
    const float* __restrict__ cb_prev,  // layer q-1 codebook [K][256] (q>0)
    const f16* __restrict__ ecat,       // this layer [K][512]
    const float* __restrict__ norms,    // this layer [K]
    const f16* __restrict__ xold,       // xb[(q-1)&1] (q>0 src; stable)
    f16* __restrict__ xnew,             // xb[q&1] (written; GEMM input)
    const float2* __restrict__ pin,     // partial layer q-1
    float2* __restrict__ pout,          // partial layer q
    float* __restrict__ idx_prev,       // [N] (q>0, slice0)
    float* __restrict__ loss_prev,      // scalar (q>0, slice0)
    int q)
{
    __shared__ f16 sEh[2][8192];      // 2 x 16 KB: 256 codes x 32 cols (eh)
    __shared__ f16 sEl[2][8192];      // 2 x 16 KB (el)
    __shared__ f16 sXh[2][8192];      // 2 x 16 KB: 256 tokens x 32 cols (xh)
    __shared__ f16 sXl[2][8192];      // 2 x 16 KB (xl)
    __shared__ float smn[256];
    __shared__ float2 smg[2][256];
    __shared__ float lred[8];

    const int tid = threadIdx.x;
    const int w = tid >> 6, l = tid & 63;
    const int wr = w >> 2, wc = w & 3;          // wr: code half, wc: token quarter
    const int l16 = l & 15, hi4 = l >> 4;

    // XCD-aligned: 4 slice-blocks of one 256-token tile share (b & 7).
    const int b = blockIdx.x;
    const int slice = (b >> 3) & 3;             // 256-code slice
    const int tokt = ((b >> 5) << 3) | (b & 7); // 64 token tiles
    const int tbase = tokt * 256;
    const int qcb = slice * 256;

    // ================= fused update phase (layer q-1 -> xnew tile) ====
    {
        const int up = tid & 15;
        const int d0 = up * 16;
        float lp = 0.f;
#pragma unroll 1
        for (int pass = 0; pass < 8; ++pass) {
            const int row = tbase + pass * 32 + (tid >> 4);
            f16* xw = xnew + (size_t)row * 512;
            if (q == 0) {
                const float* xs = x + (size_t)row * Dd + d0;
#pragma unroll
                for (int c = 0; c < 2; ++c) {
                    f16x8 hi, lo;
#pragma unroll
                    for (int j = 0; j < 8; ++j) {
                        float v = 2.f * xs[c * 8 + j];
                        f16 h = (f16)v;
                        hi[j] = h; lo[j] = (f16)(v - (float)h);
                    }
                    *(f16x8*)(xw + d0 + c * 8) = hi;
                    *(f16x8*)(xw + 256 + d0 + c * 8) = lo;
                }
            } else {
                float2 bsel = pin[row];
#pragma unroll
                for (int s2 = 1; s2 < 4; ++s2) {
                    float2 c2 = pin[(size_t)s2 * Nn + row];
                    if (c2.x > bsel.x || (c2.x == bsel.x && c2.y < bsel.y)) bsel = c2;
                }
                const int k = (int)bsel.y;
                const float* e = cb_prev + (size_t)k * Dd + d0;
                const f16* xr = xold + (size_t)row * 512;
                f16x8 h0 = *(const f16x8*)(xr + d0);
                f16x8 h1 = *(const f16x8*)(xr + d0 + 8);
                f16x8 l0 = *(const f16x8*)(xr + 256 + d0);
                f16x8 l1 = *(const f16x8*)(xr + 256 + d0 + 8);
                float rn[16];
#pragma unroll
                for (int j = 0; j < 8; ++j) {
                    rn[j]     = ((float)h0[j] + (float)l0[j]) * 0.5f - e[j];
                    rn[8 + j] = ((float)h1[j] + (float)l1[j]) * 0.5f - e[8 + j];
                }
#pragma unroll
                for (int j = 0; j < 16; ++j) lp = fmaf(rn[j], rn[j], lp);
#pragma unroll
                for (int c = 0; c < 2; ++c) {
                    f16x8 hi, lo;
#pragma unroll
                    for (int j = 0; j < 8; ++j) {
                        float v = 2.f * rn[c * 8 + j];
                        f16 h = (f16)v;
                        hi[j] = h; lo[j] = (f16)(v - (float)h);
                    }
                    *(f16x8*)(xw + d0 + c * 8) = hi;
                    *(f16x8*)(xw + 256 + d0 + c * 8) = lo;
                }
                if (slice == 0 && up == 0) idx_prev[row] = (float)k;
            }
        }
        if (q > 0 && slice == 0) {
#pragma unroll
            for (int off = 32; off >= 1; off >>= 1) lp += __shfl_down(lp, off);
            if (l == 0) lred[w] = lp;
        }
    }
    if (tid < 256) smn[tid] = norms[qcb + tid];
    __syncthreads();   // drains vmcnt(0): xnew stores visible to gload_lds
    if (q > 0 && slice == 0 && tid == 0) {
        float s = 0.f;
#pragma unroll
        for (int i = 0; i < 8; ++i) s += lred[i];
        atomicAdd(loss_prev, s * (1.0f / ((float)Nn * (float)Dd)));
    }

    // ================= GEMM phase (operand-sharing chunks) =================
    // Staging: thread t -> LDS chunk t (rows 0..127) and 512+t (rows 128..255);
    // source col-chunk pre-swizzled: g = (t&3) ^ ((t>>3)&3)  [= (row>>1)&3].
    const int srow = tid >> 2;
    const int g = ((tid & 3) ^ ((tid >> 3) & 3)) * 8;
    const f16* gae = ecat + (size_t)(qcb + srow) * 512 + g;  // eh cols [0,256), el +256
    const f16* gbx = xnew + (size_t)(tbase + srow) * 512 + g; // xh cols [0,256), xl +256

    // ds_read offsets with the same involution: cc = hi4 ^ ((row>>1)&3)
    int offA[8], offB[4];
#pragma unroll
    for (int m = 0; m < 8; ++m) {
        int row = wr * 128 + m * 16 + l16;
        offA[m] = row * 32 + ((hi4 ^ ((row >> 1) & 3)) * 8);
    }
#pragma unroll
    for (int n = 0; n < 4; ++n) {
        int row = wc * 64 + n * 16 + l16;
        offB[n] = row * 32 + ((hi4 ^ ((row >> 1) & 3)) * 8);
    }

    f32x4 acc[8][4];
#pragma unroll
    for (int m = 0; m < 8; ++m)
#pragma unroll
        for (int n = 0; n < 4; ++n) acc[m][n] = (f32x4){0.f, 0.f, 0.f, 0.f};

    // per chunk C (cols C*32..C*32+31): stage {eh, el, xh, xl} once (8 gloads)
#define STAGE_CHUNK(P, C) do { \
        int cc = (C) * 32; \
        gload16(gae + cc,             &sEh[P][tid * 8]); \
        gload16(gae + cc + 128 * 512, &sEh[P][4096 + tid * 8]); \
        gload16(gae + 256 + cc,             &sEl[P][tid * 8]); \
        gload16(gae + 256 + cc + 128 * 512, &sEl[P][4096 + tid * 8]); \
        gload16(gbx + cc,             &sXh[P][tid * 8]); \
        gload16(gbx + cc + 128 * 512, &sXh[P][4096 + tid * 8]); \
        gload16(gbx + 256 + cc,             &sXl[P][tid * 8]); \
        gload16(gbx + 256 + cc + 128 * 512, &sXl[P][4096 + tid * 8]); \
    } while (0)

    // prologue: chunk 0 staged and landed
    STAGE_CHUNK(0, 0);
    asm volatile("s_waitcnt vmcnt(0)\n\ts_barrier" ::: "memory");

#pragma unroll
    for (int c = 0; c < 8; ++c) {
        const int p = c & 1;
        if (c < 7) STAGE_CHUNK(p ^ 1, c + 1);
        // frag reads (24): aeh (shared seg1+seg3), bxh (shared seg1+seg2), bxl
        f16x8 aeh[8], bxh[4], bxl[4];
#pragma unroll
        for (int m = 0; m < 8; ++m) aeh[m] = *(const f16x8*)&sEh[p][offA[m]];
#pragma unroll
        for (int n = 0; n < 4; ++n) bxh[n] = *(const f16x8*)&sXh[p][offB[n]];
#pragma unroll
        for (int n = 0; n < 4; ++n) bxl[n] = *(const f16x8*)&sXl[p][offB[n]];
        __builtin_amdgcn_s_setprio(1);
#pragma unroll
        for (int m = 0; m < 8; ++m)          // seg1: eh * xh
#pragma unroll
            for (int n = 0; n < 4; ++n)
                acc[m][n] = __builtin_amdgcn_mfma_f32_16x16x32_f16(aeh[m], bxh[n], acc[m][n], 0, 0, 0);
#pragma unroll
        for (int m = 0; m < 8; ++m)          // seg3: eh * xl
#pragma unroll
            for (int n = 0; n < 4; ++n)
                acc[m][n] = __builtin_amdgcn_mfma_f32_16x16x32_f16(aeh[m], bxl[n], acc[m][n], 0, 0, 0);
        __builtin_amdgcn_s_setprio(0);
        // ael can reuse aeh's registers (aeh dead after seg3)
        f16x8 ael[8];
#pragma unroll
        for (int m = 0; m < 8; ++m) ael[m] = *(const f16x8*)&sEl[p][offA[m]];
        __builtin_amdgcn_s_setprio(1);
#pragma unroll
        for (int m = 0; m < 8; ++m)          // seg2: el * xh
#pragma unroll
            for (int n = 0; n < 4; ++n)
                acc[m][n] = __builtin_amdgcn_mfma_f32_16x16x32_f16(ael[m], bxh[n], acc[m][n], 0, 0, 0);
        __builtin_amdgcn_s_setprio(0);
        if (c < 7)
            asm volatile("s_waitcnt vmcnt(0)\n\ts_barrier" ::: "memory");
    }
#undef STAGE_CHUNK

    // epilogue: score = acc - |e|^2 ; top-1 (ascending code order)
    float bv[4]; int bi[4];
#pragma unroll
    for (int n = 0; n < 4; ++n) { bv[n] = -3.4e38f; bi[n] = 0; }
#pragma unroll
    for (int m = 0; m < 8; ++m) {
#pragma unroll
        for (int r = 0; r < 4; ++r) {
            int cl = wr * 128 + m * 16 + hi4 * 4 + r;   // code local in 256-slice
            float nrm = smn[cl];
            int cg = qcb + cl;
#pragma unroll
            for (int n = 0; n < 4; ++n) {
                float v = acc[m][n][r] - nrm;
                if (v > bv[n]) { bv[n] = v; bi[n] = cg; }
            }
        }
    }
    // merge across the lane>>4 groups (same token, different codes)
#pragma unroll
    for (int off = 16; off <= 32; off <<= 1) {
#pragma unroll
        for (int n = 0; n < 4; ++n) {
            float ov = __shfl_xor(bv[n], off);
            int oi = __shfl_xor(bi[n], off);
            if (ov > bv[n] || (ov == bv[n] && oi < bi[n])) { bv[n] = ov; bi[n] = oi; }
        }
    }
    if (l < 16) {
#pragma unroll
        for (int n = 0; n < 4; ++n)
            smg[wr][wc * 64 + n * 16 + l] = make_float2(bv[n], (float)bi[n]);
    }
    __syncthreads();
    // merge the two code-half wave groups
    if (tid < 256) {
        float2 a = smg[0][tid], c = smg[1][tid];
        float2 r = (c.x > a.x || (c.x == a.x && c.y < a.y)) ? c : a;
        pout[(size_t)slice * Nn + tbase + tid] = r;
    }
}

// ---- final: merge partial(7), idx7, loss7, out = x - r8 ----
__global__ __launch_bounds__(256) void final_kernel(
    const float* __restrict__ x,
    const float* __restrict__ cb7,      // layer 7 codebook
    const f16* __restrict__ xcat,       // xb[1]: holds split(2*r7)
    const float2* __restrict__ pin,     // partial layer 7
    float* __restrict__ out,
    float* __restrict__ idx7,
    float* __restrict__ loss7)
{
    __shared__ float lsum[4];
    const int tid = threadIdx.x;
    const int row = blockIdx.x * 16 + (tid >> 4);
    const int d0 = (tid & 15) * 16;

    float2 bsel = pin[row];
#pragma unroll
    for (int s2 = 1; s2 < 4; ++s2) {
        float2 c2 = pin[(size_t)s2 * Nn + row];
        if (c2.x > bsel.x || (c2.x == bsel.x && c2.y < bsel.y)) bsel = c2;
    }
    const int k = (int)bsel.y;
    const float* e = cb7 + (size_t)k * Dd + d0;
    const f16* xr = xcat + (size_t)row * 512;
    const float* xs = x + (size_t)row * Dd + d0;
    float* os = out + (size_t)row * Dd + d0;

    f16x8 h0 = *(const f16x8*)(xr + d0);
    f16x8 h1 = *(const f16x8*)(xr + d0 + 8);
    f16x8 l0 = *(const f16x8*)(xr + 256 + d0);
    f16x8 l1 = *(const f16x8*)(xr + 256 + d0 + 8);
    float lp = 0.f;
#pragma unroll
    for (int j = 0; j < 8; ++j) {
        float r7a = ((float)h0[j] + (float)l0[j]) * 0.5f;
        float r7b = ((float)h1[j] + (float)l1[j]) * 0.5f;
        float r8a = r7a - e[j];
        float r8b = r7b - e[8 + j];
        os[j]     = xs[j] - r8a;
        os[8 + j] = xs[8 + j] - r8b;
        lp = fmaf(r8a, r8a, lp);
        lp = fmaf(r8b, r8b, lp);
    }
    if ((tid & 15) == 0) idx7[row] = (float)k;

#pragma unroll
    for (int off = 32; off >= 1; off >>= 1) lp += __shfl_down(lp, off);
    if ((tid & 63) == 0) lsum[tid >> 6] = lp;
    __syncthreads();
    if (tid == 0) {
        float s = lsum[0] + lsum[1] + lsum[2] + lsum[3];
        atomicAdd(loss7, s * (1.0f / ((float)Nn * (float)Dd)));
    }
}

extern "C" void kernel_launch(void* const* d_in, const int* in_sizes, int n_in,
                              void* d_out, int out_size, void* d_ws, size_t ws_size,
                              hipStream_t stream) {
    const float* x   = (const float*)d_in[0];   // [N,D]
    const float* cbs = (const float*)d_in[1];   // [Q,K,D]
    float* out    = (float*)d_out;
    float* idxs   = out + (size_t)Nn * Dd;        // [Q*N]
    float* losses = idxs + (size_t)Qq * Nn;       // [Q]

    f16* xb0     = (f16*)d_ws;                          // [N][512]
    f16* xb1     = xb0 + (size_t)Nn * 512;              // [N][512]
    f16* ecat    = xb1 + (size_t)Nn * 512;              // [Q*K][512]
    float* norms = (float*)(ecat + (size_t)Qq * Kk * 512);  // [Q*K]
    float2* part0 = (float2*)(norms + (size_t)Qq * Kk);     // [4][N]
    float2* part1 = part0 + (size_t)4 * Nn;                 // [4][N]

    hipMemsetAsync(losses, 0, Qq * sizeof(float), stream);
    build_ecat<<<(Qq * Kk) / 8, 256, 0, stream>>>(cbs, ecat, norms);

    for (int q = 0; q < Qq; ++q) {
        float2* pin  = (q & 1) ? part1 : part0;   // layer q-1 partials
        float2* pout = (q & 1) ? part0 : part1;   // layer q partials
        const f16* xold = (q & 1) ? xb0 : xb1;    // xb[(q-1)&1]
        f16* xnew       = (q & 1) ? xb1 : xb0;    // xb[q&1]
        score_kernel<<<256, 512, 0, stream>>>(
            x,
            q > 0 ? cbs + (size_t)(q - 1) * Kk * Dd : cbs,
            ecat + (size_t)q * Kk * 512, norms + (size_t)q * Kk,
            xold, xnew, pin, pout,
            q > 0 ? idxs + (size_t)(q - 1) * Nn : idxs,
            q > 0 ? losses + (q - 1) : losses,
            q);
    }
    // layer 7 partials: q=7 odd -> pout = part0; r7 split lives in xb[1]
    final_kernel<<<Nn / 16, 256, 0, stream>>>(
        x, cbs + (size_t)7 * Kk * Dd, xb1, part0, out,
        idxs + (size_t)7 * Nn, losses + 7);
}